// Round 11
// baseline (206.325 us; speedup 1.0000x reference)
//
#include <hip/hip_runtime.h>
#include <hip/hip_bf16.h>

#define NN 20000
#define FF 128
#define HH 256
#define EDIM 128
#define GG 64
#define NEDGE 320000
#define PSUB 16
#define CSTRIDE 64   // max in-degree slot count (mean 16, sigma 4 -> 64 is ~12 sigma)

typedef __attribute__((ext_vector_type(4))) float f4;
typedef __attribute__((ext_vector_type(4))) float f32x4;
typedef __attribute__((ext_vector_type(8))) short bf16x8;
typedef __attribute__((ext_vector_type(4))) unsigned short u16x4;
typedef __attribute__((ext_vector_type(4))) int i32x4;

__device__ inline float wsum(float v) {
#pragma unroll
    for (int m = 32; m >= 1; m >>= 1) v += __shfl_xor(v, m, 64);
    return v;
}

__device__ inline unsigned short f2b(float f) {
    union { float f; unsigned u; } x; x.f = f;
    unsigned r = x.u + 0x7fffu + ((x.u >> 16) & 1u);   // RNE
    return (unsigned short)(r >> 16);
}
__device__ inline float b2f(unsigned short u) {
    union { unsigned u; float f; } x; x.u = ((unsigned)u) << 16;
    return x.f;
}

// ---------------- prep: zero cnt (20), weight transpose via LDS (56) ----------------
__global__ void k_prep(const float* __restrict__ W0, const float* __restrict__ W1,
                       const float* __restrict__ W2, const float* __restrict__ W3,
                       unsigned short* __restrict__ T0, unsigned short* __restrict__ T1,
                       unsigned short* __restrict__ T2, unsigned short* __restrict__ T3,
                       int* __restrict__ cnt) {
    int b = blockIdx.x, tid = threadIdx.x;
    if (b < 20) {
        int t = b * 256 + tid;
        if (t < NN / 4) ((i32x4*)cnt)[t] = (i32x4){0, 0, 0, 0};
        return;
    }
    const float* W; unsigned short* T; int K, tt;
    if (b < 28)      { W = W0; T = T0; K = 128; tt = b - 20; }
    else if (b < 44) { W = W1; T = T1; K = 256; tt = b - 28; }
    else if (b < 60) { W = W2; T = T2; K = 256; tt = b - 44; }
    else             { W = W3; T = T3; K = 256; tt = b - 60; }
    int ktiles = K / 64;
    int kt = tt % ktiles, nt = tt / ktiles;
    int k0 = kt * 64, n0 = nt * 64;
    __shared__ unsigned short ldsT[64][65];   // [n][k]
    int rn = (tid & 15) * 4, rk = tid >> 4;
#pragma unroll
    for (int i = 0; i < 4; i++) {
        int k = rk + 16 * i;
        f4 v = *(const f4*)(W + (size_t)(k0 + k) * 256 + n0 + rn);
#pragma unroll
        for (int j = 0; j < 4; j++) ldsT[rn + j][k] = f2b(v[j]);
    }
    __syncthreads();
    int wn = tid >> 2, kseg = (tid & 3) * 16;
#pragma unroll
    for (int q = 0; q < 4; q++) {
        u16x4 o = { ldsT[wn][kseg + q * 4 + 0], ldsT[wn][kseg + q * 4 + 1],
                    ldsT[wn][kseg + q * 4 + 2], ldsT[wn][kseg + q * 4 + 3] };
        *(u16x4*)(T + (size_t)(n0 + wn) * K + k0 + kseg + q * 4) = o;
    }
}

// ------- fused encoder + GEMM1 (blocks [0,313)) + adjacency build ([313,1563)) -------
__global__ __launch_bounds__(256) void k_encg1(
        const float* __restrict__ X, const unsigned short* __restrict__ Wt,
        const unsigned short* __restrict__ Wt1,
        const float* __restrict__ eb, const float* __restrict__ gam,
        const float* __restrict__ bet, unsigned short* __restrict__ T1out, int M,
        const int* __restrict__ src, const int* __restrict__ dst,
        int* __restrict__ cnt, int* __restrict__ colv, int ne) {
    __shared__ unsigned short Wl[2 * 16 * 64 * 8];   // 32 KB enc-W ping-pong
    __shared__ unsigned short hs[64 * 256];          // 32 KB h tile (XOR-swizzled rows)
    int b = blockIdx.x, tid = threadIdx.x;
    if (b >= 313) {   // ---- edge build ----
        int e = (b - 313) * 256 + tid;
        if (e < ne) {
            int d = dst[e];
            int pos = atomicAdd(&cnt[d], 1);
            if (pos < CSTRIDE) colv[(size_t)d * CSTRIDE + pos] = src[e];
        }
        return;
    }
    int wave = tid >> 6, lane = tid & 63;
    int lmod = lane & 15, ldiv = lane >> 4;
    int mbase = b * 64 + wave * 16;
    int row = min(mbase + lmod, M - 1);
    f32x4 acc[16] = {};
#pragma unroll
    for (int h = 0; h < 2; h++) {
        __syncthreads();
        for (int c = tid; c < 2048; c += 256) {
            int l = c & 63, nf = (c >> 6) & 15, kss = c >> 10;
            int n = nf * 16 + (l & 15);
            int k = (h * 2 + kss) * 32 + (l >> 4) * 8;
            *(bf16x8*)(Wl + (size_t)c * 8) = *(const bf16x8*)(Wt + (size_t)n * 128 + k);
        }
        __syncthreads();
#pragma unroll
        for (int kss = 0; kss < 2; kss++) {
            int ks = h * 2 + kss;
            f4 xa = *(const f4*)(X + (size_t)row * 128 + ks * 32 + ldiv * 8);
            f4 xb2 = *(const f4*)(X + (size_t)row * 128 + ks * 32 + ldiv * 8 + 4);
            bf16x8 xf;
            xf[0] = (short)f2b(xa[0]); xf[1] = (short)f2b(xa[1]);
            xf[2] = (short)f2b(xa[2]); xf[3] = (short)f2b(xa[3]);
            xf[4] = (short)f2b(xb2[0]); xf[5] = (short)f2b(xb2[1]);
            xf[6] = (short)f2b(xb2[2]); xf[7] = (short)f2b(xb2[3]);
#pragma unroll
            for (int nf = 0; nf < 16; nf++) {
                bf16x8 wf = *(bf16x8*)(Wl + ((size_t)(kss * 16 + nf) * 64 + lane) * 8);
                acc[nf] = __builtin_amdgcn_mfma_f32_16x16x32_bf16(wf, xf, acc[nf], 0, 0, 0);
            }
        }
    }
    float vs = 0.f;
#pragma unroll
    for (int nf = 0; nf < 16; nf++) {
        f4 bb = *(const f4*)(eb + nf * 16 + ldiv * 4);
#pragma unroll
        for (int r = 0; r < 4; r++) { acc[nf][r] += bb[r]; vs += acc[nf][r]; }
    }
    vs += __shfl_xor(vs, 16, 64); vs += __shfl_xor(vs, 32, 64);
    float mean = vs * (1.0f / 256.0f);
    float ss = 0.f;
#pragma unroll
    for (int nf = 0; nf < 16; nf++) {
#pragma unroll
        for (int r = 0; r < 4; r++) { float d = acc[nf][r] - mean; ss += d * d; }
    }
    ss += __shfl_xor(ss, 16, 64); ss += __shfl_xor(ss, 32, 64);
    float rs = rsqrtf(ss * (1.0f / 256.0f) + 1e-5f);
    int r_loc = wave * 16 + lmod;
    int swz = (r_loc & 7) << 4;
#pragma unroll
    for (int nf = 0; nf < 16; nf++) {
        f4 gv = *(const f4*)(gam + nf * 16 + ldiv * 4);
        f4 bv = *(const f4*)(bet + nf * 16 + ldiv * 4);
        u16x4 o;
#pragma unroll
        for (int r = 0; r < 4; r++)
            o[r] = f2b(fmaxf((acc[nf][r] - mean) * rs * gv[r] + bv[r], 0.0f));
        int byte = ((nf * 32 + ldiv * 8) ^ swz);
        *(u16x4*)((char*)hs + (size_t)r_loc * 512 + byte) = o;
    }
    __syncthreads();
    // phase B: T1 = h @ W1
    f32x4 acc2[4][4] = {};
    const unsigned short* wb = Wt1 + (size_t)(wave * 64 + lmod) * 256 + ldiv * 8;
#pragma unroll
    for (int ks = 0; ks < 8; ks++) {
        bf16x8 wf[4], hf[4];
#pragma unroll
        for (int nf = 0; nf < 4; nf++)
            wf[nf] = *(const bf16x8*)(wb + (size_t)nf * 16 * 256 + ks * 32);
#pragma unroll
        for (int rg = 0; rg < 4; rg++) {
            int rr = rg * 16 + lmod;
            int byte = ((ks * 64 + ldiv * 16) ^ ((rr & 7) << 4));
            hf[rg] = *(const bf16x8*)((const char*)hs + (size_t)rr * 512 + byte);
        }
#pragma unroll
        for (int rg = 0; rg < 4; rg++) {
#pragma unroll
            for (int nf = 0; nf < 4; nf++) {
                acc2[rg][nf] = __builtin_amdgcn_mfma_f32_16x16x32_bf16(
                    wf[nf], hf[rg], acc2[rg][nf], 0, 0, 0);
            }
        }
    }
#pragma unroll
    for (int rg = 0; rg < 4; rg++) {
        int m = b * 64 + rg * 16 + lmod;
        if (m < M) {
#pragma unroll
            for (int nf = 0; nf < 4; nf++) {
                int n = wave * 64 + nf * 16 + ldiv * 4;
                u16x4 o = { f2b(acc2[rg][nf][0]), f2b(acc2[rg][nf][1]),
                            f2b(acc2[rg][nf][2]), f2b(acc2[rg][nf][3]) };
                *(u16x4*)(T1out + (size_t)m * 256 + n) = o;
            }
        }
    }
}

// ------- fused GCN layer: agg+bias+LN+relu(+resid) -> x_out, then T_next = x @ Wn -------
// 1024 threads = 16 waves, wave-per-node (16 nodes/block, grid 1250).
// Phase A identical math to k_aggln; row also parked in swizzled LDS.
// Phase B: wave w computes T_next[16 nodes][w*16..+15] with 8 MFMAs, W frags from L2.
__global__ __launch_bounds__(1024) void k_agg_gemm(
        const unsigned short* __restrict__ T, const int* __restrict__ cnt,
        const int* __restrict__ col,
        const float* __restrict__ b, const float* __restrict__ gam,
        const float* __restrict__ bet, const unsigned short* __restrict__ resid,
        unsigned short* __restrict__ x_out,
        const unsigned short* __restrict__ Wtn, unsigned short* __restrict__ Tnext,
        int n) {
    __shared__ unsigned short hs[16 * 256];   // 8 KB, XOR-swizzled rows
    int tid = threadIdx.x;
    int wave = tid >> 6, lane = tid & 63;
    int wid = blockIdx.x * 16 + wave;
    // ---- phase A: aggregate + LN (+resid) ----
    int deg = min(cnt[wid], CSTRIDE);
    const int* cr = col + (size_t)wid * CSTRIDE;
    f4 a0 = {0.f,0.f,0.f,0.f}, a1 = {0.f,0.f,0.f,0.f};
    f4 a2 = {0.f,0.f,0.f,0.f}, a3 = {0.f,0.f,0.f,0.f};
    int e = 0;
    for (; e + 7 < deg; e += 8) {
        i32x4 cA = *(const i32x4*)(cr + e);
        i32x4 cB = *(const i32x4*)(cr + e + 4);
        u16x4 r0 = ((const u16x4*)(T + (size_t)cA[0] * HH))[lane];
        u16x4 r1 = ((const u16x4*)(T + (size_t)cA[1] * HH))[lane];
        u16x4 r2 = ((const u16x4*)(T + (size_t)cA[2] * HH))[lane];
        u16x4 r3 = ((const u16x4*)(T + (size_t)cA[3] * HH))[lane];
        u16x4 r4 = ((const u16x4*)(T + (size_t)cB[0] * HH))[lane];
        u16x4 r5 = ((const u16x4*)(T + (size_t)cB[1] * HH))[lane];
        u16x4 r6 = ((const u16x4*)(T + (size_t)cB[2] * HH))[lane];
        u16x4 r7 = ((const u16x4*)(T + (size_t)cB[3] * HH))[lane];
        float w0 = rsqrtf((float)(cnt[cA[0]] + 1));
        float w1 = rsqrtf((float)(cnt[cA[1]] + 1));
        float w2 = rsqrtf((float)(cnt[cA[2]] + 1));
        float w3 = rsqrtf((float)(cnt[cA[3]] + 1));
        float w4 = rsqrtf((float)(cnt[cB[0]] + 1));
        float w5 = rsqrtf((float)(cnt[cB[1]] + 1));
        float w6 = rsqrtf((float)(cnt[cB[2]] + 1));
        float w7 = rsqrtf((float)(cnt[cB[3]] + 1));
#pragma unroll
        for (int i = 0; i < 4; i++) {
            a0[i] = fmaf(w0, b2f(r0[i]), a0[i]);
            a1[i] = fmaf(w1, b2f(r1[i]), a1[i]);
            a2[i] = fmaf(w2, b2f(r2[i]), a2[i]);
            a3[i] = fmaf(w3, b2f(r3[i]), a3[i]);
            a0[i] = fmaf(w4, b2f(r4[i]), a0[i]);
            a1[i] = fmaf(w5, b2f(r5[i]), a1[i]);
            a2[i] = fmaf(w6, b2f(r6[i]), a2[i]);
            a3[i] = fmaf(w7, b2f(r7[i]), a3[i]);
        }
    }
    for (; e + 3 < deg; e += 4) {
        i32x4 c4 = *(const i32x4*)(cr + e);
        float w0 = rsqrtf((float)(cnt[c4[0]] + 1));
        float w1 = rsqrtf((float)(cnt[c4[1]] + 1));
        float w2 = rsqrtf((float)(cnt[c4[2]] + 1));
        float w3 = rsqrtf((float)(cnt[c4[3]] + 1));
        u16x4 r0 = ((const u16x4*)(T + (size_t)c4[0] * HH))[lane];
        u16x4 r1 = ((const u16x4*)(T + (size_t)c4[1] * HH))[lane];
        u16x4 r2 = ((const u16x4*)(T + (size_t)c4[2] * HH))[lane];
        u16x4 r3 = ((const u16x4*)(T + (size_t)c4[3] * HH))[lane];
#pragma unroll
        for (int i = 0; i < 4; i++) {
            a0[i] = fmaf(w0, b2f(r0[i]), a0[i]);
            a1[i] = fmaf(w1, b2f(r1[i]), a1[i]);
            a2[i] = fmaf(w2, b2f(r2[i]), a2[i]);
            a3[i] = fmaf(w3, b2f(r3[i]), a3[i]);
        }
    }
    for (; e < deg; e++) {
        int s0 = cr[e];
        float w0 = rsqrtf((float)(cnt[s0] + 1));
        u16x4 r0 = ((const u16x4*)(T + (size_t)s0 * HH))[lane];
#pragma unroll
        for (int i = 0; i < 4; i++) a0[i] = fmaf(w0, b2f(r0[i]), a0[i]);
    }
    float di = rsqrtf((float)(deg + 1));
    u16x4 sv = ((const u16x4*)(T + (size_t)wid * HH))[lane];
    f4 bb = ((const f4*)b)[lane];
    f4 v;
#pragma unroll
    for (int i = 0; i < 4; i++)
        v[i] = di * (a0[i] + a1[i] + a2[i] + a3[i]) + (di * di) * b2f(sv[i]) + bb[i];
    float s = wsum(v[0] + v[1] + v[2] + v[3]);
    float mean = s * (1.0f / HH);
    f4 d = v - mean;
    float ss = wsum(d[0] * d[0] + d[1] * d[1] + d[2] * d[2] + d[3] * d[3]);
    float rs = rsqrtf(ss * (1.0f / HH) + 1e-5f);
    f4 gv = ((const f4*)gam)[lane], bv = ((const f4*)bet)[lane];
    f4 o = d * rs * gv + bv;
#pragma unroll
    for (int i = 0; i < 4; i++) o[i] = fmaxf(o[i], 0.0f);
    if (resid != nullptr) {
        u16x4 rv = ((const u16x4*)(resid + (size_t)wid * HH))[lane];
#pragma unroll
        for (int i = 0; i < 4; i++) o[i] += b2f(rv[i]);
    }
    u16x4 ov;
#pragma unroll
    for (int i = 0; i < 4; i++) ov[i] = f2b(o[i]);
    ((u16x4*)(x_out + (size_t)wid * HH))[lane] = ov;
    // park row in swizzled LDS: row = wave, lane covers bytes lane*8..+7
    *(u16x4*)((char*)hs + (size_t)wave * 512 + ((lane * 8) ^ ((wave & 7) << 4))) = ov;
    __syncthreads();
    // ---- phase B: T_next[16 nodes][wave*16..+15] = x_tile @ Wn ----
    int lmod = lane & 15, ldiv = lane >> 4;
    f32x4 acc2 = {};
    const unsigned short* wb = Wtn + (size_t)(wave * 16 + lmod) * 256 + ldiv * 8;
#pragma unroll
    for (int ks = 0; ks < 8; ks++) {
        bf16x8 wf = *(const bf16x8*)(wb + ks * 32);
        int byte = ((ks * 64 + ldiv * 16) ^ ((lmod & 7) << 4));
        bf16x8 hf = *(const bf16x8*)((const char*)hs + (size_t)lmod * 512 + byte);
        acc2 = __builtin_amdgcn_mfma_f32_16x16x32_bf16(wf, hf, acc2, 0, 0, 0);
    }
    int m = blockIdx.x * 16 + lmod;
    u16x4 oo = { f2b(acc2[0]), f2b(acc2[1]), f2b(acc2[2]), f2b(acc2[3]) };
    *(u16x4*)(Tnext + (size_t)m * 256 + wave * 16 + ldiv * 4) = oo;
}

// ------------- layer-3 GCN agg + LN + relu + resid + fused attention logit -------------
__global__ void k_aggln(const unsigned short* __restrict__ T, const int* __restrict__ cnt,
                        const int* __restrict__ col,
                        const float* __restrict__ b, const float* __restrict__ gam,
                        const float* __restrict__ bet, const unsigned short* __restrict__ resid,
                        unsigned short* __restrict__ out,
                        const float* __restrict__ aw, const float* __restrict__ ab,
                        float* __restrict__ elog, int n) {
    int wid = (blockIdx.x * blockDim.x + threadIdx.x) >> 6;
    int lane = threadIdx.x & 63;
    if (wid >= n) return;
    int deg = min(cnt[wid], CSTRIDE);
    const int* cr = col + (size_t)wid * CSTRIDE;
    f4 a0 = {0.f,0.f,0.f,0.f}, a1 = {0.f,0.f,0.f,0.f};
    f4 a2 = {0.f,0.f,0.f,0.f}, a3 = {0.f,0.f,0.f,0.f};
    int e = 0;
    for (; e + 7 < deg; e += 8) {
        i32x4 cA = *(const i32x4*)(cr + e);
        i32x4 cB = *(const i32x4*)(cr + e + 4);
        u16x4 r0 = ((const u16x4*)(T + (size_t)cA[0] * HH))[lane];
        u16x4 r1 = ((const u16x4*)(T + (size_t)cA[1] * HH))[lane];
        u16x4 r2 = ((const u16x4*)(T + (size_t)cA[2] * HH))[lane];
        u16x4 r3 = ((const u16x4*)(T + (size_t)cA[3] * HH))[lane];
        u16x4 r4 = ((const u16x4*)(T + (size_t)cB[0] * HH))[lane];
        u16x4 r5 = ((const u16x4*)(T + (size_t)cB[1] * HH))[lane];
        u16x4 r6 = ((const u16x4*)(T + (size_t)cB[2] * HH))[lane];
        u16x4 r7 = ((const u16x4*)(T + (size_t)cB[3] * HH))[lane];
        float w0 = rsqrtf((float)(cnt[cA[0]] + 1));
        float w1 = rsqrtf((float)(cnt[cA[1]] + 1));
        float w2 = rsqrtf((float)(cnt[cA[2]] + 1));
        float w3 = rsqrtf((float)(cnt[cA[3]] + 1));
        float w4 = rsqrtf((float)(cnt[cB[0]] + 1));
        float w5 = rsqrtf((float)(cnt[cB[1]] + 1));
        float w6 = rsqrtf((float)(cnt[cB[2]] + 1));
        float w7 = rsqrtf((float)(cnt[cB[3]] + 1));
#pragma unroll
        for (int i = 0; i < 4; i++) {
            a0[i] = fmaf(w0, b2f(r0[i]), a0[i]);
            a1[i] = fmaf(w1, b2f(r1[i]), a1[i]);
            a2[i] = fmaf(w2, b2f(r2[i]), a2[i]);
            a3[i] = fmaf(w3, b2f(r3[i]), a3[i]);
            a0[i] = fmaf(w4, b2f(r4[i]), a0[i]);
            a1[i] = fmaf(w5, b2f(r5[i]), a1[i]);
            a2[i] = fmaf(w6, b2f(r6[i]), a2[i]);
            a3[i] = fmaf(w7, b2f(r7[i]), a3[i]);
        }
    }
    for (; e + 3 < deg; e += 4) {
        i32x4 c4 = *(const i32x4*)(cr + e);
        float w0 = rsqrtf((float)(cnt[c4[0]] + 1));
        float w1 = rsqrtf((float)(cnt[c4[1]] + 1));
        float w2 = rsqrtf((float)(cnt[c4[2]] + 1));
        float w3 = rsqrtf((float)(cnt[c4[3]] + 1));
        u16x4 r0 = ((const u16x4*)(T + (size_t)c4[0] * HH))[lane];
        u16x4 r1 = ((const u16x4*)(T + (size_t)c4[1] * HH))[lane];
        u16x4 r2 = ((const u16x4*)(T + (size_t)c4[2] * HH))[lane];
        u16x4 r3 = ((const u16x4*)(T + (size_t)c4[3] * HH))[lane];
#pragma unroll
        for (int i = 0; i < 4; i++) {
            a0[i] = fmaf(w0, b2f(r0[i]), a0[i]);
            a1[i] = fmaf(w1, b2f(r1[i]), a1[i]);
            a2[i] = fmaf(w2, b2f(r2[i]), a2[i]);
            a3[i] = fmaf(w3, b2f(r3[i]), a3[i]);
        }
    }
    for (; e < deg; e++) {
        int s0 = cr[e];
        float w0 = rsqrtf((float)(cnt[s0] + 1));
        u16x4 r0 = ((const u16x4*)(T + (size_t)s0 * HH))[lane];
#pragma unroll
        for (int i = 0; i < 4; i++) a0[i] = fmaf(w0, b2f(r0[i]), a0[i]);
    }
    float di = rsqrtf((float)(deg + 1));
    u16x4 sv = ((const u16x4*)(T + (size_t)wid * HH))[lane];
    f4 bb = ((const f4*)b)[lane];
    f4 v;
#pragma unroll
    for (int i = 0; i < 4; i++)
        v[i] = di * (a0[i] + a1[i] + a2[i] + a3[i]) + (di * di) * b2f(sv[i]) + bb[i];
    float s = wsum(v[0] + v[1] + v[2] + v[3]);
    float mean = s * (1.0f / HH);
    f4 d = v - mean;
    float ss = wsum(d[0] * d[0] + d[1] * d[1] + d[2] * d[2] + d[3] * d[3]);
    float rs = rsqrtf(ss * (1.0f / HH) + 1e-5f);
    f4 gv = ((const f4*)gam)[lane], bv = ((const f4*)bet)[lane];
    f4 o = d * rs * gv + bv;
#pragma unroll
    for (int i = 0; i < 4; i++) o[i] = fmaxf(o[i], 0.0f);
    if (resid != nullptr) {
        u16x4 rv = ((const u16x4*)(resid + (size_t)wid * HH))[lane];
#pragma unroll
        for (int i = 0; i < 4; i++) o[i] += b2f(rv[i]);
    }
    u16x4 ov;
#pragma unroll
    for (int i = 0; i < 4; i++) ov[i] = f2b(o[i]);
    ((u16x4*)(out + (size_t)wid * HH))[lane] = ov;
    if (elog != nullptr) {
        f4 wv = ((const f4*)aw)[lane];
        float dotv = wsum(b2f(ov[0]) * wv[0] + b2f(ov[1]) * wv[1] +
                          b2f(ov[2]) * wv[2] + b2f(ov[3]) * wv[3]);
        if (lane == 0) elog[wid] = expf(tanhf(dotv + ab[0]));
    }
}

// ---------------- pooling: partial weighted feature sums + partial elog sums ----------------
__device__ inline int lbound(const int* __restrict__ arr, int n, int key) {
    int lo = 0, hi = n;
    while (lo < hi) {
        int mid = (lo + hi) >> 1;
        if (arr[mid] < key) lo = mid + 1; else hi = mid;
    }
    return lo;
}

__global__ __launch_bounds__(256) void k_pool(const unsigned short* __restrict__ x3,
                                              const float* __restrict__ elog,
                                              const int* __restrict__ batch,
                                              float* __restrict__ partial,
                                              float* __restrict__ esum, int n) {
    int g = blockIdx.y, s = blockIdx.x, j = threadIdx.x;
    __shared__ int slo, shi;
    if (j == 0) { slo = lbound(batch, n, g); shi = lbound(batch, n, g + 1); }
    __syncthreads();
    int lo = slo, hi = shi;
    float a0 = 0.f, a1 = 0.f;
    int i = lo + s;
    for (; i + PSUB < hi; i += 2 * PSUB) {
        a0 += elog[i] * b2f(x3[(size_t)i * HH + j]);
        a1 += elog[i + PSUB] * b2f(x3[(size_t)(i + PSUB) * HH + j]);
    }
    if (i < hi) a0 += elog[i] * b2f(x3[(size_t)i * HH + j]);
    partial[(size_t)(g * PSUB + s) * HH + j] = a0 + a1;
    if (j < 64) {
        float es = 0.f;
        for (int t = j; (size_t)lo + s + (size_t)t * PSUB < (size_t)hi; t += 64)
            es += elog[lo + s + t * PSUB];
        es = wsum(es);
        if (j == 0) esum[g * PSUB + s] = es;
    }
}

// ---------------- tail: global elog sum + partial reduce + MLP + LN + project + L2 ----------------
__global__ __launch_bounds__(256) void k_tail(
    const float* __restrict__ partial, const float* __restrict__ esum,
    const float* __restrict__ pw1, const float* __restrict__ pb1,
    const float* __restrict__ pg, const float* __restrict__ pbe,
    const float* __restrict__ pw2, const float* __restrict__ pb2,
    float* __restrict__ out) {
    __shared__ float pl[256];
    __shared__ float ps[256];
    __shared__ float red[256];
    __shared__ float os[128];
    int g = blockIdx.x, j = threadIdx.x;
    float t = esum[j] + esum[j + 256] + esum[j + 512] + esum[j + 768];
    red[j] = t;
    __syncthreads();
    for (int s = 128; s > 0; s >>= 1) {
        if (j < s) red[j] += red[j + s];
        __syncthreads();
    }
    float inv = 1.0f / red[0];
    __syncthreads();
    float acc = 0.f;
#pragma unroll
    for (int s = 0; s < PSUB; s++) acc += partial[(size_t)(g * PSUB + s) * HH + j];
    pl[j] = acc * inv;
    __syncthreads();
    float q = pb1[j];
#pragma unroll 8
    for (int k = 0; k < 256; k++) q = fmaf(pl[k], pw1[k * 256 + j], q);
    red[j] = q;
    __syncthreads();
    for (int s = 128; s > 0; s >>= 1) {
        if (j < s) red[j] += red[j + s];
        __syncthreads();
    }
    float mean = red[0] * (1.0f / 256.0f);
    __syncthreads();
    float d = q - mean;
    red[j] = d * d;
    __syncthreads();
    for (int s = 128; s > 0; s >>= 1) {
        if (j < s) red[j] += red[j + s];
        __syncthreads();
    }
    float var = red[0] * (1.0f / 256.0f);
    __syncthreads();
    float p = fmaxf(d * rsqrtf(var + 1e-5f) * pg[j] + pbe[j], 0.0f);
    ps[j] = p;
    __syncthreads();
    if (j < 128) {
        float o = pb2[j];
#pragma unroll 8
        for (int k = 0; k < 256; k++) o = fmaf(ps[k], pw2[k * 128 + j], o);
        os[j] = o;
    }
    __syncthreads();
    float val = (j < 128) ? os[j] * os[j] : 0.f;
    red[j] = val;
    __syncthreads();
    for (int s = 128; s > 0; s >>= 1) {
        if (j < s) red[j] += red[j + s];
        __syncthreads();
    }
    float nrm = fmaxf(sqrtf(red[0]), 1e-12f);
    if (j < 128) out[g * 128 + j] = os[j] / nrm;
}

// ---------------- host ----------------
extern "C" void kernel_launch(void* const* d_in, const int* in_sizes, int n_in,
                              void* d_out, int out_size, void* d_ws, size_t ws_size,
                              hipStream_t stream) {
    const float* x      = (const float*)d_in[0];
    const int*   ei     = (const int*)d_in[1];
    const int*   batch  = (const int*)d_in[2];
    const float* enc_w  = (const float*)d_in[3];
    const float* enc_b  = (const float*)d_in[4];
    const float* enc_g  = (const float*)d_in[5];
    const float* enc_be = (const float*)d_in[6];
    const float* w1 = (const float*)d_in[7],  *b1 = (const float*)d_in[8];
    const float* g1 = (const float*)d_in[9],  *be1 = (const float*)d_in[10];
    const float* w2 = (const float*)d_in[11], *b2 = (const float*)d_in[12];
    const float* g2 = (const float*)d_in[13], *be2 = (const float*)d_in[14];
    const float* w3 = (const float*)d_in[15], *b3 = (const float*)d_in[16];
    const float* g3 = (const float*)d_in[17], *be3 = (const float*)d_in[18];
    const float* attn_w = (const float*)d_in[19], *attn_b = (const float*)d_in[20];
    const float* pw1 = (const float*)d_in[21], *pb1 = (const float*)d_in[22];
    const float* pg  = (const float*)d_in[23], *pbe = (const float*)d_in[24];
    const float* pw2 = (const float*)d_in[25], *pb2 = (const float*)d_in[26];
    float* out = (float*)d_out;

    const int* src = ei;
    const int* dst = ei + NEDGE;

    // bf16 region: 4 feature buffers + transposed weights
    unsigned short* us = (unsigned short*)d_ws;
    unsigned short* Tb = us;                              // [NN,HH] T1, later T3
    unsigned short* Pb = Tb + (size_t)NN * HH;            // [NN,HH] x2
    unsigned short* Qb = Pb + (size_t)NN * HH;            // [NN,HH] x1, later x3
    unsigned short* Ub = Qb + (size_t)NN * HH;            // [NN,HH] T2
    unsigned short* wte = Ub + (size_t)NN * HH;           // [256*128]
    unsigned short* wt1 = wte + 256 * 128;                // [256*256]
    unsigned short* wt2 = wt1 + 256 * 256;
    unsigned short* wt3 = wt2 + 256 * 256;
    // fp32/int region (16B-aligned by construction)
    float* fp = (float*)(wt3 + 256 * 256);
    float* elog    = fp;                                  // [NN]
    float* partial = elog + NN;                           // [GG*PSUB*HH]
    float* esum    = partial + (size_t)GG * PSUB * HH;    // [GG*PSUB]
    int* cnt = (int*)(esum + GG * PSUB);                  // [NN]
    int* col = cnt + NN;                                  // [NN*CSTRIDE]

    // prep: zero cnt + transpose weights (76 blocks)
    k_prep<<<76, 256, 0, stream>>>(enc_w, w1, w2, w3, wte, wt1, wt2, wt3, cnt);
    // fused encoder GEMM+LN+GEMM1 -> T1=Tb (313 blocks) + edge build (1250 blocks)
    k_encg1<<<313 + 1250, 256, 0, stream>>>(x, wte, wt1, enc_b, enc_g, enc_be, Tb, NN,
                                            src, dst, cnt, col, NEDGE);
    // layer 1 fused: gather T1=Tb -> x1=Qb ; T2 = x1 @ W2 -> Ub
    k_agg_gemm<<<NN / 16, 1024, 0, stream>>>(Tb, cnt, col, b1, g1, be1, nullptr,
                                             Qb, wt2, Ub, NN);
    // layer 2 fused: gather T2=Ub (resid x1=Qb) -> x2=Pb ; T3 = x2 @ W3 -> Tb
    k_agg_gemm<<<NN / 16, 1024, 0, stream>>>(Ub, cnt, col, b2, g2, be2, Qb,
                                             Pb, wt3, Tb, NN);
    // layer 3: gather T3=Tb (resid x2=Pb) -> x3=Qb + attention logits
    k_aggln<<<(NN + 3) / 4, 256, 0, stream>>>(Tb, cnt, col, b3, g3, be3, Pb, Qb,
                                              attn_w, attn_b, elog, NN);
    // pooling + tail
    k_pool<<<dim3(PSUB, GG), 256, 0, stream>>>(Qb, elog, batch, partial, esum, NN);
    k_tail<<<GG, 256, 0, stream>>>(partial, esum, pw1, pb1, pg, pbe, pw2, pb2, out);
}

// Round 12
// 182.704 us; speedup vs baseline: 1.1293x; 1.1293x over previous
//
#include <hip/hip_runtime.h>
#include <hip/hip_bf16.h>

#define NN 20000
#define FF 128
#define HH 256
#define EDIM 128
#define GG 64
#define NEDGE 320000
#define PSUB 16
#define CSTRIDE 64   // max in-degree slot count (mean 16, sigma 4 -> 64 is ~12 sigma)

typedef __attribute__((ext_vector_type(4))) float f4;
typedef __attribute__((ext_vector_type(4))) float f32x4;
typedef __attribute__((ext_vector_type(8))) short bf16x8;
typedef __attribute__((ext_vector_type(4))) unsigned short u16x4;
typedef __attribute__((ext_vector_type(4))) int i32x4;

__device__ inline float wsum(float v) {
#pragma unroll
    for (int m = 32; m >= 1; m >>= 1) v += __shfl_xor(v, m, 64);
    return v;
}

__device__ inline unsigned short f2b(float f) {
    union { float f; unsigned u; } x; x.f = f;
    unsigned r = x.u + 0x7fffu + ((x.u >> 16) & 1u);   // RNE
    return (unsigned short)(r >> 16);
}
__device__ inline float b2f(unsigned short u) {
    union { unsigned u; float f; } x; x.u = ((unsigned)u) << 16;
    return x.f;
}

// ---------------- prep: zero cnt (20), weight transpose via LDS (56) ----------------
__global__ void k_prep(const float* __restrict__ W0, const float* __restrict__ W1,
                       const float* __restrict__ W2, const float* __restrict__ W3,
                       unsigned short* __restrict__ T0, unsigned short* __restrict__ T1,
                       unsigned short* __restrict__ T2, unsigned short* __restrict__ T3,
                       int* __restrict__ cnt) {
    int b = blockIdx.x, tid = threadIdx.x;
    if (b < 20) {
        int t = b * 256 + tid;
        if (t < NN / 4) ((i32x4*)cnt)[t] = (i32x4){0, 0, 0, 0};
        return;
    }
    const float* W; unsigned short* T; int K, tt;
    if (b < 28)      { W = W0; T = T0; K = 128; tt = b - 20; }
    else if (b < 44) { W = W1; T = T1; K = 256; tt = b - 28; }
    else if (b < 60) { W = W2; T = T2; K = 256; tt = b - 44; }
    else             { W = W3; T = T3; K = 256; tt = b - 60; }
    int ktiles = K / 64;
    int kt = tt % ktiles, nt = tt / ktiles;
    int k0 = kt * 64, n0 = nt * 64;
    __shared__ unsigned short ldsT[64][65];   // [n][k]
    int rn = (tid & 15) * 4, rk = tid >> 4;
#pragma unroll
    for (int i = 0; i < 4; i++) {
        int k = rk + 16 * i;
        f4 v = *(const f4*)(W + (size_t)(k0 + k) * 256 + n0 + rn);
#pragma unroll
        for (int j = 0; j < 4; j++) ldsT[rn + j][k] = f2b(v[j]);
    }
    __syncthreads();
    int wn = tid >> 2, kseg = (tid & 3) * 16;
#pragma unroll
    for (int q = 0; q < 4; q++) {
        u16x4 o = { ldsT[wn][kseg + q * 4 + 0], ldsT[wn][kseg + q * 4 + 1],
                    ldsT[wn][kseg + q * 4 + 2], ldsT[wn][kseg + q * 4 + 3] };
        *(u16x4*)(T + (size_t)(n0 + wn) * K + k0 + kseg + q * 4) = o;
    }
}

// ------- fused encoder + GEMM1 (blocks [0,313)) + adjacency build ([313,1563)) -------
// Phase A: h = relu(LN(x @ enc_w + b)) for 64 rows, h kept in regs -> swizzled LDS.
// Phase B: T1 = h @ W1 straight from LDS h-tile + L2-resident W1. h never touches HBM.
__global__ __launch_bounds__(256) void k_encg1(
        const float* __restrict__ X, const unsigned short* __restrict__ Wt,
        const unsigned short* __restrict__ Wt1,
        const float* __restrict__ eb, const float* __restrict__ gam,
        const float* __restrict__ bet, unsigned short* __restrict__ T1out, int M,
        const int* __restrict__ src, const int* __restrict__ dst,
        int* __restrict__ cnt, int* __restrict__ colv, int ne) {
    __shared__ unsigned short Wl[2 * 16 * 64 * 8];   // 32 KB enc-W ping-pong
    __shared__ unsigned short hs[64 * 256];          // 32 KB h tile (XOR-swizzled rows)
    int b = blockIdx.x, tid = threadIdx.x;
    if (b >= 313) {   // ---- edge build ----
        int e = (b - 313) * 256 + tid;
        if (e < ne) {
            int d = dst[e];
            int pos = atomicAdd(&cnt[d], 1);
            if (pos < CSTRIDE) colv[(size_t)d * CSTRIDE + pos] = src[e];
        }
        return;
    }
    int wave = tid >> 6, lane = tid & 63;
    int lmod = lane & 15, ldiv = lane >> 4;
    int mbase = b * 64 + wave * 16;
    int row = min(mbase + lmod, M - 1);
    f32x4 acc[16] = {};
#pragma unroll
    for (int h = 0; h < 2; h++) {
        __syncthreads();
        for (int c = tid; c < 2048; c += 256) {
            int l = c & 63, nf = (c >> 6) & 15, kss = c >> 10;
            int n = nf * 16 + (l & 15);
            int k = (h * 2 + kss) * 32 + (l >> 4) * 8;
            *(bf16x8*)(Wl + (size_t)c * 8) = *(const bf16x8*)(Wt + (size_t)n * 128 + k);
        }
        __syncthreads();
#pragma unroll
        for (int kss = 0; kss < 2; kss++) {
            int ks = h * 2 + kss;
            f4 xa = *(const f4*)(X + (size_t)row * 128 + ks * 32 + ldiv * 8);
            f4 xb2 = *(const f4*)(X + (size_t)row * 128 + ks * 32 + ldiv * 8 + 4);
            bf16x8 xf;
            xf[0] = (short)f2b(xa[0]); xf[1] = (short)f2b(xa[1]);
            xf[2] = (short)f2b(xa[2]); xf[3] = (short)f2b(xa[3]);
            xf[4] = (short)f2b(xb2[0]); xf[5] = (short)f2b(xb2[1]);
            xf[6] = (short)f2b(xb2[2]); xf[7] = (short)f2b(xb2[3]);
#pragma unroll
            for (int nf = 0; nf < 16; nf++) {
                bf16x8 wf = *(bf16x8*)(Wl + ((size_t)(kss * 16 + nf) * 64 + lane) * 8);
                acc[nf] = __builtin_amdgcn_mfma_f32_16x16x32_bf16(wf, xf, acc[nf], 0, 0, 0);
            }
        }
    }
    float vs = 0.f;
#pragma unroll
    for (int nf = 0; nf < 16; nf++) {
        f4 bb = *(const f4*)(eb + nf * 16 + ldiv * 4);
#pragma unroll
        for (int r = 0; r < 4; r++) { acc[nf][r] += bb[r]; vs += acc[nf][r]; }
    }
    vs += __shfl_xor(vs, 16, 64); vs += __shfl_xor(vs, 32, 64);
    float mean = vs * (1.0f / 256.0f);
    float ss = 0.f;
#pragma unroll
    for (int nf = 0; nf < 16; nf++) {
#pragma unroll
        for (int r = 0; r < 4; r++) { float d = acc[nf][r] - mean; ss += d * d; }
    }
    ss += __shfl_xor(ss, 16, 64); ss += __shfl_xor(ss, 32, 64);
    float rs = rsqrtf(ss * (1.0f / 256.0f) + 1e-5f);
    int r_loc = wave * 16 + lmod;
    int swz = (r_loc & 7) << 4;
#pragma unroll
    for (int nf = 0; nf < 16; nf++) {
        f4 gv = *(const f4*)(gam + nf * 16 + ldiv * 4);
        f4 bv = *(const f4*)(bet + nf * 16 + ldiv * 4);
        u16x4 o;
#pragma unroll
        for (int r = 0; r < 4; r++)
            o[r] = f2b(fmaxf((acc[nf][r] - mean) * rs * gv[r] + bv[r], 0.0f));
        int byte = ((nf * 32 + ldiv * 8) ^ swz);
        *(u16x4*)((char*)hs + (size_t)r_loc * 512 + byte) = o;
    }
    __syncthreads();
    // phase B: T1 = h @ W1
    f32x4 acc2[4][4] = {};
    const unsigned short* wb = Wt1 + (size_t)(wave * 64 + lmod) * 256 + ldiv * 8;
#pragma unroll
    for (int ks = 0; ks < 8; ks++) {
        bf16x8 wf[4], hf[4];
#pragma unroll
        for (int nf = 0; nf < 4; nf++)
            wf[nf] = *(const bf16x8*)(wb + (size_t)nf * 16 * 256 + ks * 32);
#pragma unroll
        for (int rg = 0; rg < 4; rg++) {
            int rr = rg * 16 + lmod;
            int byte = ((ks * 64 + ldiv * 16) ^ ((rr & 7) << 4));
            hf[rg] = *(const bf16x8*)((const char*)hs + (size_t)rr * 512 + byte);
        }
#pragma unroll
        for (int rg = 0; rg < 4; rg++) {
#pragma unroll
            for (int nf = 0; nf < 4; nf++) {
                acc2[rg][nf] = __builtin_amdgcn_mfma_f32_16x16x32_bf16(
                    wf[nf], hf[rg], acc2[rg][nf], 0, 0, 0);
            }
        }
    }
#pragma unroll
    for (int rg = 0; rg < 4; rg++) {
        int m = b * 64 + rg * 16 + lmod;
        if (m < M) {
#pragma unroll
            for (int nf = 0; nf < 4; nf++) {
                int n = wave * 64 + nf * 16 + ldiv * 4;
                u16x4 o = { f2b(acc2[rg][nf][0]), f2b(acc2[rg][nf][1]),
                            f2b(acc2[rg][nf][2]), f2b(acc2[rg][nf][3]) };
                *(u16x4*)(T1out + (size_t)m * 256 + n) = o;
            }
        }
    }
}

// ---------------- bf16 MFMA GEMM with LDS W panel (layers 2-3) ----------------
#define GEMM_NWG 628
template<int K>
__global__ __launch_bounds__(256) void bgemm(const unsigned short* __restrict__ Xb,
                                             const unsigned short* __restrict__ Wt,
                                             unsigned short* __restrict__ C, int M) {
    constexpr int KSTEPS = K / 32;
    __shared__ unsigned short Wl[KSTEPS * 4 * 64 * 8];
    int tid = threadIdx.x;
    int orig = blockIdx.y * 4 + blockIdx.x;
    int xcd = orig & 7, rest = orig >> 3;
    constexpr int q = GEMM_NWG >> 3, r = GEMM_NWG & 7;
    int wg = (xcd < r ? xcd * (q + 1) : r * (q + 1) + (xcd - r) * q) + rest;
    int m0 = wg >> 2;
    int n0 = (wg & 3) * 64;
    for (int c = tid; c < KSTEPS * 4 * 64; c += 256) {
        int lc = c & 63;
        int nf = (c >> 6) & 3;
        int ks = c >> 8;
        int n = n0 + nf * 16 + (lc & 15);
        int k = ks * 32 + (lc >> 4) * 8;
        bf16x8 v = *(const bf16x8*)(Wt + (size_t)n * K + k);
        *(bf16x8*)(Wl + (size_t)c * 8) = v;
    }
    __syncthreads();
    int wave = tid >> 6, lane = tid & 63;
    int lmod = lane & 15, ldiv = lane >> 4;
    int mbase = m0 * 128 + wave * 32;
    f32x4 acc[2][4] = {};
#pragma unroll
    for (int ks = 0; ks < KSTEPS; ks++) {
        int k0 = ks * 32 + ldiv * 8;
        bf16x8 xf[2], wf[4];
#pragma unroll
        for (int mf = 0; mf < 2; mf++) {
            int row = mbase + mf * 16 + lmod;
            row = min(row, M - 1);
            xf[mf] = *(const bf16x8*)(Xb + (size_t)row * K + k0);
        }
#pragma unroll
        for (int nf = 0; nf < 4; nf++) {
            wf[nf] = *(const bf16x8*)(Wl + ((size_t)(ks * 4 + nf) * 64 + lane) * 8);
        }
#pragma unroll
        for (int mf = 0; mf < 2; mf++) {
#pragma unroll
            for (int nf = 0; nf < 4; nf++) {
                acc[mf][nf] = __builtin_amdgcn_mfma_f32_16x16x32_bf16(
                    wf[nf], xf[mf], acc[mf][nf], 0, 0, 0);
            }
        }
    }
#pragma unroll
    for (int mf = 0; mf < 2; mf++) {
        int m = mbase + mf * 16 + lmod;
        if (m < M) {
#pragma unroll
            for (int nf = 0; nf < 4; nf++) {
                int n = n0 + nf * 16 + ldiv * 4;
                u16x4 o = { f2b(acc[mf][nf][0]), f2b(acc[mf][nf][1]),
                            f2b(acc[mf][nf][2]), f2b(acc[mf][nf][3]) };
                *(u16x4*)(C + (size_t)m * 256 + n) = o;
            }
        }
    }
}

// ------------- GCN agg + bias + LN + relu (+ residual) (+ fused attention logit) -------------
__global__ void k_aggln(const unsigned short* __restrict__ T, const int* __restrict__ cnt,
                        const int* __restrict__ col,
                        const float* __restrict__ b, const float* __restrict__ gam,
                        const float* __restrict__ bet, const unsigned short* __restrict__ resid,
                        unsigned short* __restrict__ out,
                        const float* __restrict__ aw, const float* __restrict__ ab,
                        float* __restrict__ elog, int n) {
    int wid = (blockIdx.x * blockDim.x + threadIdx.x) >> 6;
    int lane = threadIdx.x & 63;
    if (wid >= n) return;
    int deg = min(cnt[wid], CSTRIDE);
    const int* cr = col + (size_t)wid * CSTRIDE;
    f4 a0 = {0.f,0.f,0.f,0.f}, a1 = {0.f,0.f,0.f,0.f};
    f4 a2 = {0.f,0.f,0.f,0.f}, a3 = {0.f,0.f,0.f,0.f};
    int e = 0;
    for (; e + 7 < deg; e += 8) {
        i32x4 cA = *(const i32x4*)(cr + e);
        i32x4 cB = *(const i32x4*)(cr + e + 4);
        u16x4 r0 = ((const u16x4*)(T + (size_t)cA[0] * HH))[lane];
        u16x4 r1 = ((const u16x4*)(T + (size_t)cA[1] * HH))[lane];
        u16x4 r2 = ((const u16x4*)(T + (size_t)cA[2] * HH))[lane];
        u16x4 r3 = ((const u16x4*)(T + (size_t)cA[3] * HH))[lane];
        u16x4 r4 = ((const u16x4*)(T + (size_t)cB[0] * HH))[lane];
        u16x4 r5 = ((const u16x4*)(T + (size_t)cB[1] * HH))[lane];
        u16x4 r6 = ((const u16x4*)(T + (size_t)cB[2] * HH))[lane];
        u16x4 r7 = ((const u16x4*)(T + (size_t)cB[3] * HH))[lane];
        float w0 = rsqrtf((float)(cnt[cA[0]] + 1));
        float w1 = rsqrtf((float)(cnt[cA[1]] + 1));
        float w2 = rsqrtf((float)(cnt[cA[2]] + 1));
        float w3 = rsqrtf((float)(cnt[cA[3]] + 1));
        float w4 = rsqrtf((float)(cnt[cB[0]] + 1));
        float w5 = rsqrtf((float)(cnt[cB[1]] + 1));
        float w6 = rsqrtf((float)(cnt[cB[2]] + 1));
        float w7 = rsqrtf((float)(cnt[cB[3]] + 1));
#pragma unroll
        for (int i = 0; i < 4; i++) {
            a0[i] = fmaf(w0, b2f(r0[i]), a0[i]);
            a1[i] = fmaf(w1, b2f(r1[i]), a1[i]);
            a2[i] = fmaf(w2, b2f(r2[i]), a2[i]);
            a3[i] = fmaf(w3, b2f(r3[i]), a3[i]);
            a0[i] = fmaf(w4, b2f(r4[i]), a0[i]);
            a1[i] = fmaf(w5, b2f(r5[i]), a1[i]);
            a2[i] = fmaf(w6, b2f(r6[i]), a2[i]);
            a3[i] = fmaf(w7, b2f(r7[i]), a3[i]);
        }
    }
    for (; e + 3 < deg; e += 4) {
        i32x4 c4 = *(const i32x4*)(cr + e);
        float w0 = rsqrtf((float)(cnt[c4[0]] + 1));
        float w1 = rsqrtf((float)(cnt[c4[1]] + 1));
        float w2 = rsqrtf((float)(cnt[c4[2]] + 1));
        float w3 = rsqrtf((float)(cnt[c4[3]] + 1));
        u16x4 r0 = ((const u16x4*)(T + (size_t)c4[0] * HH))[lane];
        u16x4 r1 = ((const u16x4*)(T + (size_t)c4[1] * HH))[lane];
        u16x4 r2 = ((const u16x4*)(T + (size_t)c4[2] * HH))[lane];
        u16x4 r3 = ((const u16x4*)(T + (size_t)c4[3] * HH))[lane];
#pragma unroll
        for (int i = 0; i < 4; i++) {
            a0[i] = fmaf(w0, b2f(r0[i]), a0[i]);
            a1[i] = fmaf(w1, b2f(r1[i]), a1[i]);
            a2[i] = fmaf(w2, b2f(r2[i]), a2[i]);
            a3[i] = fmaf(w3, b2f(r3[i]), a3[i]);
        }
    }
    for (; e < deg; e++) {
        int s0 = cr[e];
        float w0 = rsqrtf((float)(cnt[s0] + 1));
        u16x4 r0 = ((const u16x4*)(T + (size_t)s0 * HH))[lane];
#pragma unroll
        for (int i = 0; i < 4; i++) a0[i] = fmaf(w0, b2f(r0[i]), a0[i]);
    }
    float di = rsqrtf((float)(deg + 1));
    u16x4 sv = ((const u16x4*)(T + (size_t)wid * HH))[lane];
    f4 bb = ((const f4*)b)[lane];
    f4 v;
#pragma unroll
    for (int i = 0; i < 4; i++)
        v[i] = di * (a0[i] + a1[i] + a2[i] + a3[i]) + (di * di) * b2f(sv[i]) + bb[i];
    float s = wsum(v[0] + v[1] + v[2] + v[3]);
    float mean = s * (1.0f / HH);
    f4 d = v - mean;
    float ss = wsum(d[0] * d[0] + d[1] * d[1] + d[2] * d[2] + d[3] * d[3]);
    float rs = rsqrtf(ss * (1.0f / HH) + 1e-5f);
    f4 gv = ((const f4*)gam)[lane], bv = ((const f4*)bet)[lane];
    f4 o = d * rs * gv + bv;
#pragma unroll
    for (int i = 0; i < 4; i++) o[i] = fmaxf(o[i], 0.0f);
    if (resid != nullptr) {
        u16x4 rv = ((const u16x4*)(resid + (size_t)wid * HH))[lane];
#pragma unroll
        for (int i = 0; i < 4; i++) o[i] += b2f(rv[i]);
    }
    u16x4 ov;
#pragma unroll
    for (int i = 0; i < 4; i++) ov[i] = f2b(o[i]);
    ((u16x4*)(out + (size_t)wid * HH))[lane] = ov;
    if (elog != nullptr) {
        f4 wv = ((const f4*)aw)[lane];
        float dotv = wsum(b2f(ov[0]) * wv[0] + b2f(ov[1]) * wv[1] +
                          b2f(ov[2]) * wv[2] + b2f(ov[3]) * wv[3]);
        if (lane == 0) elog[wid] = expf(tanhf(dotv + ab[0]));
    }
}

// ---------------- pooling: partial weighted feature sums + partial elog sums ----------------
__device__ inline int lbound(const int* __restrict__ arr, int n, int key) {
    int lo = 0, hi = n;
    while (lo < hi) {
        int mid = (lo + hi) >> 1;
        if (arr[mid] < key) lo = mid + 1; else hi = mid;
    }
    return lo;
}

__global__ __launch_bounds__(256) void k_pool(const unsigned short* __restrict__ x3,
                                              const float* __restrict__ elog,
                                              const int* __restrict__ batch,
                                              float* __restrict__ partial,
                                              float* __restrict__ esum, int n) {
    int g = blockIdx.y, s = blockIdx.x, j = threadIdx.x;
    __shared__ int slo, shi;
    if (j == 0) { slo = lbound(batch, n, g); shi = lbound(batch, n, g + 1); }
    __syncthreads();
    int lo = slo, hi = shi;
    float a0 = 0.f, a1 = 0.f;
    int i = lo + s;
    for (; i + PSUB < hi; i += 2 * PSUB) {
        a0 += elog[i] * b2f(x3[(size_t)i * HH + j]);
        a1 += elog[i + PSUB] * b2f(x3[(size_t)(i + PSUB) * HH + j]);
    }
    if (i < hi) a0 += elog[i] * b2f(x3[(size_t)i * HH + j]);
    partial[(size_t)(g * PSUB + s) * HH + j] = a0 + a1;
    if (j < 64) {
        float es = 0.f;
        for (int t = j; (size_t)lo + s + (size_t)t * PSUB < (size_t)hi; t += 64)
            es += elog[lo + s + t * PSUB];
        es = wsum(es);
        if (j == 0) esum[g * PSUB + s] = es;
    }
}

// ---------------- tail: global elog sum + partial reduce + MLP + LN + project + L2 ----------------
__global__ __launch_bounds__(256) void k_tail(
    const float* __restrict__ partial, const float* __restrict__ esum,
    const float* __restrict__ pw1, const float* __restrict__ pb1,
    const float* __restrict__ pg, const float* __restrict__ pbe,
    const float* __restrict__ pw2, const float* __restrict__ pb2,
    float* __restrict__ out) {
    __shared__ float pl[256];
    __shared__ float ps[256];
    __shared__ float red[256];
    __shared__ float os[128];
    int g = blockIdx.x, j = threadIdx.x;
    float t = esum[j] + esum[j + 256] + esum[j + 512] + esum[j + 768];
    red[j] = t;
    __syncthreads();
    for (int s = 128; s > 0; s >>= 1) {
        if (j < s) red[j] += red[j + s];
        __syncthreads();
    }
    float inv = 1.0f / red[0];
    __syncthreads();
    float acc = 0.f;
#pragma unroll
    for (int s = 0; s < PSUB; s++) acc += partial[(size_t)(g * PSUB + s) * HH + j];
    pl[j] = acc * inv;
    __syncthreads();
    float q = pb1[j];
#pragma unroll 8
    for (int k = 0; k < 256; k++) q = fmaf(pl[k], pw1[k * 256 + j], q);
    red[j] = q;
    __syncthreads();
    for (int s = 128; s > 0; s >>= 1) {
        if (j < s) red[j] += red[j + s];
        __syncthreads();
    }
    float mean = red[0] * (1.0f / 256.0f);
    __syncthreads();
    float d = q - mean;
    red[j] = d * d;
    __syncthreads();
    for (int s = 128; s > 0; s >>= 1) {
        if (j < s) red[j] += red[j + s];
        __syncthreads();
    }
    float var = red[0] * (1.0f / 256.0f);
    __syncthreads();
    float p = fmaxf(d * rsqrtf(var + 1e-5f) * pg[j] + pbe[j], 0.0f);
    ps[j] = p;
    __syncthreads();
    if (j < 128) {
        float o = pb2[j];
#pragma unroll 8
        for (int k = 0; k < 256; k++) o = fmaf(ps[k], pw2[k * 128 + j], o);
        os[j] = o;
    }
    __syncthreads();
    float val = (j < 128) ? os[j] * os[j] : 0.f;
    red[j] = val;
    __syncthreads();
    for (int s = 128; s > 0; s >>= 1) {
        if (j < s) red[j] += red[j + s];
        __syncthreads();
    }
    float nrm = fmaxf(sqrtf(red[0]), 1e-12f);
    if (j < 128) out[g * 128 + j] = os[j] / nrm;
}

// ---------------- host ----------------
extern "C" void kernel_launch(void* const* d_in, const int* in_sizes, int n_in,
                              void* d_out, int out_size, void* d_ws, size_t ws_size,
                              hipStream_t stream) {
    const float* x      = (const float*)d_in[0];
    const int*   ei     = (const int*)d_in[1];
    const int*   batch  = (const int*)d_in[2];
    const float* enc_w  = (const float*)d_in[3];
    const float* enc_b  = (const float*)d_in[4];
    const float* enc_g  = (const float*)d_in[5];
    const float* enc_be = (const float*)d_in[6];
    const float* w1 = (const float*)d_in[7],  *b1 = (const float*)d_in[8];
    const float* g1 = (const float*)d_in[9],  *be1 = (const float*)d_in[10];
    const float* w2 = (const float*)d_in[11], *b2 = (const float*)d_in[12];
    const float* g2 = (const float*)d_in[13], *be2 = (const float*)d_in[14];
    const float* w3 = (const float*)d_in[15], *b3 = (const float*)d_in[16];
    const float* g3 = (const float*)d_in[17], *be3 = (const float*)d_in[18];
    const float* attn_w = (const float*)d_in[19], *attn_b = (const float*)d_in[20];
    const float* pw1 = (const float*)d_in[21], *pb1 = (const float*)d_in[22];
    const float* pg  = (const float*)d_in[23], *pbe = (const float*)d_in[24];
    const float* pw2 = (const float*)d_in[25], *pb2 = (const float*)d_in[26];
    float* out = (float*)d_out;

    const int* src = ei;
    const int* dst = ei + NEDGE;

    // bf16 region
    unsigned short* us = (unsigned short*)d_ws;
    unsigned short* Tb = us;                              // [NN,HH] T1, later T2/T3
    unsigned short* Pb = Tb + (size_t)NN * HH;            // [NN,HH] x2
    unsigned short* Qb = Pb + (size_t)NN * HH;            // [NN,HH] x1, then x3
    unsigned short* wte = Qb + (size_t)NN * HH;           // [256*128]
    unsigned short* wt1 = wte + 256 * 128;                // [256*256]
    unsigned short* wt2 = wt1 + 256 * 256;
    unsigned short* wt3 = wt2 + 256 * 256;
    // fp32/int region (16B-aligned by construction)
    float* fp = (float*)(wt3 + 256 * 256);
    float* elog    = fp;                                  // [NN]
    float* partial = elog + NN;                           // [GG*PSUB*HH]
    float* esum    = partial + (size_t)GG * PSUB * HH;    // [GG*PSUB]
    int* cnt = (int*)(esum + GG * PSUB);                  // [NN]
    int* col = cnt + NN;                                  // [NN*CSTRIDE]

    // prep: zero cnt + transpose weights (76 blocks)
    k_prep<<<76, 256, 0, stream>>>(enc_w, w1, w2, w3, wte, wt1, wt2, wt3, cnt);
    // fused encoder GEMM+LN+GEMM1 -> T1 (313 blocks) + edge build (1250 blocks)
    k_encg1<<<313 + 1250, 256, 0, stream>>>(x, wte, wt1, enc_b, enc_g, enc_be, Tb, NN,
                                            src, dst, cnt, col, NEDGE);

    dim3 gg(4, 157);   // 628 blocks, 128-row tiles (LDS W panel, XCD remap)
    // layer 1: T1=Tb -> x1=Qb
    k_aggln<<<(NN + 3) / 4, 256, 0, stream>>>(Tb, cnt, col, b1, g1, be1, nullptr, Qb,
                                              nullptr, nullptr, nullptr, NN);
    // layer 2: x1=Qb -> T2=Tb -> x2=Pb (resid Qb)
    bgemm<256><<<gg, 256, 0, stream>>>(Qb, wt2, Tb, NN);
    k_aggln<<<(NN + 3) / 4, 256, 0, stream>>>(Tb, cnt, col, b2, g2, be2, Qb, Pb,
                                              nullptr, nullptr, nullptr, NN);
    // layer 3: x2=Pb -> T3=Tb -> x3=Qb (resid Pb), fused attention logits
    bgemm<256><<<gg, 256, 0, stream>>>(Pb, wt3, Tb, NN);
    k_aggln<<<(NN + 3) / 4, 256, 0, stream>>>(Tb, cnt, col, b3, g3, be3, Pb, Qb,
                                              attn_w, attn_b, elog, NN);
    // pooling + tail
    k_pool<<<dim3(PSUB, GG), 256, 0, stream>>>(Qb, elog, batch, partial, esum, NN);
    k_tail<<<GG, 256, 0, stream>>>(partial, esum, pw1, pb1, pg, pbe, pw2, pb2, out);
}

// Round 13
// 161.868 us; speedup vs baseline: 1.2746x; 1.1287x over previous
//
#include <hip/hip_runtime.h>
#include <hip/hip_bf16.h>

#define NN 20000
#define FF 128
#define HH 256
#define EDIM 128
#define GG 64
#define NEDGE 320000
#define PSUB 16
#define CSTRIDE 64   // max in-degree slot count (mean 16, sigma 4 -> 64 is ~12 sigma)

typedef __attribute__((ext_vector_type(4))) float f4;
typedef __attribute__((ext_vector_type(2))) float f2;
typedef __attribute__((ext_vector_type(4))) float f32x4;
typedef __attribute__((ext_vector_type(8))) short bf16x8;
typedef __attribute__((ext_vector_type(4))) unsigned short u16x4;
typedef __attribute__((ext_vector_type(4))) int i32x4;

__device__ inline float wsum(float v) {
#pragma unroll
    for (int m = 32; m >= 1; m >>= 1) v += __shfl_xor(v, m, 64);
    return v;
}

__device__ inline unsigned short f2b(float f) {
    union { float f; unsigned u; } x; x.f = f;
    unsigned r = x.u + 0x7fffu + ((x.u >> 16) & 1u);   // RNE
    return (unsigned short)(r >> 16);
}
__device__ inline float b2f(unsigned short u) {
    union { unsigned u; float f; } x; x.u = ((unsigned)u) << 16;
    return x.f;
}

// ---- fp8 e4m3 (OCP, gfx950 HW cvt) pack/unpack: 4 features per dword ----
__device__ inline f4 fp8x4_to_f4(unsigned int u) {
    f2 lo = __builtin_amdgcn_cvt_pk_f32_fp8(u, false);   // bytes 0,1
    f2 hi = __builtin_amdgcn_cvt_pk_f32_fp8(u, true);    // bytes 2,3
    f4 r; r[0] = lo[0]; r[1] = lo[1]; r[2] = hi[0]; r[3] = hi[1];
    return r;
}
__device__ inline unsigned int f4_to_fp8x4(f4 v) {
    unsigned int r = 0;
    r = __builtin_amdgcn_cvt_pk_fp8_f32(v[0], v[1], r, false);
    r = __builtin_amdgcn_cvt_pk_fp8_f32(v[2], v[3], r, true);
    return r;
}

// ---------------- prep: zero cnt (20), weight transpose via LDS (56) ----------------
__global__ void k_prep(const float* __restrict__ W0, const float* __restrict__ W1,
                       const float* __restrict__ W2, const float* __restrict__ W3,
                       unsigned short* __restrict__ T0, unsigned short* __restrict__ T1,
                       unsigned short* __restrict__ T2, unsigned short* __restrict__ T3,
                       int* __restrict__ cnt) {
    int b = blockIdx.x, tid = threadIdx.x;
    if (b < 20) {
        int t = b * 256 + tid;
        if (t < NN / 4) ((i32x4*)cnt)[t] = (i32x4){0, 0, 0, 0};
        return;
    }
    const float* W; unsigned short* T; int K, tt;
    if (b < 28)      { W = W0; T = T0; K = 128; tt = b - 20; }
    else if (b < 44) { W = W1; T = T1; K = 256; tt = b - 28; }
    else if (b < 60) { W = W2; T = T2; K = 256; tt = b - 44; }
    else             { W = W3; T = T3; K = 256; tt = b - 60; }
    int ktiles = K / 64;
    int kt = tt % ktiles, nt = tt / ktiles;
    int k0 = kt * 64, n0 = nt * 64;
    __shared__ unsigned short ldsT[64][65];   // [n][k]
    int rn = (tid & 15) * 4, rk = tid >> 4;
#pragma unroll
    for (int i = 0; i < 4; i++) {
        int k = rk + 16 * i;
        f4 v = *(const f4*)(W + (size_t)(k0 + k) * 256 + n0 + rn);
#pragma unroll
        for (int j = 0; j < 4; j++) ldsT[rn + j][k] = f2b(v[j]);
    }
    __syncthreads();
    int wn = tid >> 2, kseg = (tid & 3) * 16;
#pragma unroll
    for (int q = 0; q < 4; q++) {
        u16x4 o = { ldsT[wn][kseg + q * 4 + 0], ldsT[wn][kseg + q * 4 + 1],
                    ldsT[wn][kseg + q * 4 + 2], ldsT[wn][kseg + q * 4 + 3] };
        *(u16x4*)(T + (size_t)(n0 + wn) * K + k0 + kseg + q * 4) = o;
    }
}

// ------- fused encoder + GEMM1 (blocks [0,313)) + adjacency build ([313,1563)) -------
// Phase A: h = relu(LN(x @ enc_w + b)), h in regs -> swizzled LDS.
// Phase B: T1 = h @ W1, stored fp8 e4m3 (aggregation operand).
__global__ __launch_bounds__(256) void k_encg1(
        const float* __restrict__ X, const unsigned short* __restrict__ Wt,
        const unsigned short* __restrict__ Wt1,
        const float* __restrict__ eb, const float* __restrict__ gam,
        const float* __restrict__ bet, unsigned char* __restrict__ T1out, int M,
        const int* __restrict__ src, const int* __restrict__ dst,
        int* __restrict__ cnt, int* __restrict__ colv, int ne) {
    __shared__ unsigned short Wl[2 * 16 * 64 * 8];   // 32 KB enc-W ping-pong
    __shared__ unsigned short hs[64 * 256];          // 32 KB h tile (XOR-swizzled rows)
    int b = blockIdx.x, tid = threadIdx.x;
    if (b >= 313) {   // ---- edge build ----
        int e = (b - 313) * 256 + tid;
        if (e < ne) {
            int d = dst[e];
            int pos = atomicAdd(&cnt[d], 1);
            if (pos < CSTRIDE) colv[(size_t)d * CSTRIDE + pos] = src[e];
        }
        return;
    }
    int wave = tid >> 6, lane = tid & 63;
    int lmod = lane & 15, ldiv = lane >> 4;
    int mbase = b * 64 + wave * 16;
    int row = min(mbase + lmod, M - 1);
    f32x4 acc[16] = {};
#pragma unroll
    for (int h = 0; h < 2; h++) {
        __syncthreads();
        for (int c = tid; c < 2048; c += 256) {
            int l = c & 63, nf = (c >> 6) & 15, kss = c >> 10;
            int n = nf * 16 + (l & 15);
            int k = (h * 2 + kss) * 32 + (l >> 4) * 8;
            *(bf16x8*)(Wl + (size_t)c * 8) = *(const bf16x8*)(Wt + (size_t)n * 128 + k);
        }
        __syncthreads();
#pragma unroll
        for (int kss = 0; kss < 2; kss++) {
            int ks = h * 2 + kss;
            f4 xa = *(const f4*)(X + (size_t)row * 128 + ks * 32 + ldiv * 8);
            f4 xb2 = *(const f4*)(X + (size_t)row * 128 + ks * 32 + ldiv * 8 + 4);
            bf16x8 xf;
            xf[0] = (short)f2b(xa[0]); xf[1] = (short)f2b(xa[1]);
            xf[2] = (short)f2b(xa[2]); xf[3] = (short)f2b(xa[3]);
            xf[4] = (short)f2b(xb2[0]); xf[5] = (short)f2b(xb2[1]);
            xf[6] = (short)f2b(xb2[2]); xf[7] = (short)f2b(xb2[3]);
#pragma unroll
            for (int nf = 0; nf < 16; nf++) {
                bf16x8 wf = *(bf16x8*)(Wl + ((size_t)(kss * 16 + nf) * 64 + lane) * 8);
                acc[nf] = __builtin_amdgcn_mfma_f32_16x16x32_bf16(wf, xf, acc[nf], 0, 0, 0);
            }
        }
    }
    float vs = 0.f;
#pragma unroll
    for (int nf = 0; nf < 16; nf++) {
        f4 bb = *(const f4*)(eb + nf * 16 + ldiv * 4);
#pragma unroll
        for (int r = 0; r < 4; r++) { acc[nf][r] += bb[r]; vs += acc[nf][r]; }
    }
    vs += __shfl_xor(vs, 16, 64); vs += __shfl_xor(vs, 32, 64);
    float mean = vs * (1.0f / 256.0f);
    float ss = 0.f;
#pragma unroll
    for (int nf = 0; nf < 16; nf++) {
#pragma unroll
        for (int r = 0; r < 4; r++) { float d = acc[nf][r] - mean; ss += d * d; }
    }
    ss += __shfl_xor(ss, 16, 64); ss += __shfl_xor(ss, 32, 64);
    float rs = rsqrtf(ss * (1.0f / 256.0f) + 1e-5f);
    int r_loc = wave * 16 + lmod;
    int swz = (r_loc & 7) << 4;
#pragma unroll
    for (int nf = 0; nf < 16; nf++) {
        f4 gv = *(const f4*)(gam + nf * 16 + ldiv * 4);
        f4 bv = *(const f4*)(bet + nf * 16 + ldiv * 4);
        u16x4 o;
#pragma unroll
        for (int r = 0; r < 4; r++)
            o[r] = f2b(fmaxf((acc[nf][r] - mean) * rs * gv[r] + bv[r], 0.0f));
        int byte = ((nf * 32 + ldiv * 8) ^ swz);
        *(u16x4*)((char*)hs + (size_t)r_loc * 512 + byte) = o;
    }
    __syncthreads();
    // phase B: T1 = h @ W1 -> fp8
    f32x4 acc2[4][4] = {};
    const unsigned short* wb = Wt1 + (size_t)(wave * 64 + lmod) * 256 + ldiv * 8;
#pragma unroll
    for (int ks = 0; ks < 8; ks++) {
        bf16x8 wf[4], hf[4];
#pragma unroll
        for (int nf = 0; nf < 4; nf++)
            wf[nf] = *(const bf16x8*)(wb + (size_t)nf * 16 * 256 + ks * 32);
#pragma unroll
        for (int rg = 0; rg < 4; rg++) {
            int rr = rg * 16 + lmod;
            int byte = ((ks * 64 + ldiv * 16) ^ ((rr & 7) << 4));
            hf[rg] = *(const bf16x8*)((const char*)hs + (size_t)rr * 512 + byte);
        }
#pragma unroll
        for (int rg = 0; rg < 4; rg++) {
#pragma unroll
            for (int nf = 0; nf < 4; nf++) {
                acc2[rg][nf] = __builtin_amdgcn_mfma_f32_16x16x32_bf16(
                    wf[nf], hf[rg], acc2[rg][nf], 0, 0, 0);
            }
        }
    }
#pragma unroll
    for (int rg = 0; rg < 4; rg++) {
        int m = b * 64 + rg * 16 + lmod;
        if (m < M) {
#pragma unroll
            for (int nf = 0; nf < 4; nf++) {
                int n = wave * 64 + nf * 16 + ldiv * 4;
                f4 av = { acc2[rg][nf][0], acc2[rg][nf][1],
                          acc2[rg][nf][2], acc2[rg][nf][3] };
                *(unsigned int*)(T1out + (size_t)m * 256 + n) = f4_to_fp8x4(av);
            }
        }
    }
}

// ---------------- bf16-in / fp8-out MFMA GEMM with LDS W panel (layers 2-3) ----------------
#define GEMM_NWG 628
template<int K>
__global__ __launch_bounds__(256) void bgemm(const unsigned short* __restrict__ Xb,
                                             const unsigned short* __restrict__ Wt,
                                             unsigned char* __restrict__ C, int M) {
    constexpr int KSTEPS = K / 32;
    __shared__ unsigned short Wl[KSTEPS * 4 * 64 * 8];
    int tid = threadIdx.x;
    int orig = blockIdx.y * 4 + blockIdx.x;
    int xcd = orig & 7, rest = orig >> 3;
    constexpr int q = GEMM_NWG >> 3, r = GEMM_NWG & 7;
    int wg = (xcd < r ? xcd * (q + 1) : r * (q + 1) + (xcd - r) * q) + rest;
    int m0 = wg >> 2;
    int n0 = (wg & 3) * 64;
    for (int c = tid; c < KSTEPS * 4 * 64; c += 256) {
        int lc = c & 63;
        int nf = (c >> 6) & 3;
        int ks = c >> 8;
        int n = n0 + nf * 16 + (lc & 15);
        int k = ks * 32 + (lc >> 4) * 8;
        bf16x8 v = *(const bf16x8*)(Wt + (size_t)n * K + k);
        *(bf16x8*)(Wl + (size_t)c * 8) = v;
    }
    __syncthreads();
    int wave = tid >> 6, lane = tid & 63;
    int lmod = lane & 15, ldiv = lane >> 4;
    int mbase = m0 * 128 + wave * 32;
    f32x4 acc[2][4] = {};
#pragma unroll
    for (int ks = 0; ks < KSTEPS; ks++) {
        int k0 = ks * 32 + ldiv * 8;
        bf16x8 xf[2], wf[4];
#pragma unroll
        for (int mf = 0; mf < 2; mf++) {
            int row = mbase + mf * 16 + lmod;
            row = min(row, M - 1);
            xf[mf] = *(const bf16x8*)(Xb + (size_t)row * K + k0);
        }
#pragma unroll
        for (int nf = 0; nf < 4; nf++) {
            wf[nf] = *(const bf16x8*)(Wl + ((size_t)(ks * 4 + nf) * 64 + lane) * 8);
        }
#pragma unroll
        for (int mf = 0; mf < 2; mf++) {
#pragma unroll
            for (int nf = 0; nf < 4; nf++) {
                acc[mf][nf] = __builtin_amdgcn_mfma_f32_16x16x32_bf16(
                    wf[nf], xf[mf], acc[mf][nf], 0, 0, 0);
            }
        }
    }
#pragma unroll
    for (int mf = 0; mf < 2; mf++) {
        int m = mbase + mf * 16 + lmod;
        if (m < M) {
#pragma unroll
            for (int nf = 0; nf < 4; nf++) {
                int n = n0 + nf * 16 + ldiv * 4;
                f4 av = { acc[mf][nf][0], acc[mf][nf][1],
                          acc[mf][nf][2], acc[mf][nf][3] };
                *(unsigned int*)(C + (size_t)m * 256 + n) = f4_to_fp8x4(av);
            }
        }
    }
}

// ------- GCN agg (fp8 T) + bias + LN + relu (+ residual) (+ fused attention logit) -------
__global__ void k_aggln(const unsigned char* __restrict__ T, const int* __restrict__ cnt,
                        const int* __restrict__ col,
                        const float* __restrict__ b, const float* __restrict__ gam,
                        const float* __restrict__ bet, const unsigned short* __restrict__ resid,
                        unsigned short* __restrict__ out,
                        const float* __restrict__ aw, const float* __restrict__ ab,
                        float* __restrict__ elog, int n) {
    int wid = (blockIdx.x * blockDim.x + threadIdx.x) >> 6;
    int lane = threadIdx.x & 63;
    if (wid >= n) return;
    int deg = min(cnt[wid], CSTRIDE);
    const int* cr = col + (size_t)wid * CSTRIDE;
    f4 a0 = {0.f,0.f,0.f,0.f}, a1 = {0.f,0.f,0.f,0.f};
    f4 a2 = {0.f,0.f,0.f,0.f}, a3 = {0.f,0.f,0.f,0.f};
    int e = 0;
    for (; e + 7 < deg; e += 8) {          // 8 independent 256B row loads in flight
        i32x4 cA = *(const i32x4*)(cr + e);
        i32x4 cB = *(const i32x4*)(cr + e + 4);
        unsigned int r0 = ((const unsigned int*)(T + (size_t)cA[0] * 256))[lane];
        unsigned int r1 = ((const unsigned int*)(T + (size_t)cA[1] * 256))[lane];
        unsigned int r2 = ((const unsigned int*)(T + (size_t)cA[2] * 256))[lane];
        unsigned int r3 = ((const unsigned int*)(T + (size_t)cA[3] * 256))[lane];
        unsigned int r4 = ((const unsigned int*)(T + (size_t)cB[0] * 256))[lane];
        unsigned int r5 = ((const unsigned int*)(T + (size_t)cB[1] * 256))[lane];
        unsigned int r6 = ((const unsigned int*)(T + (size_t)cB[2] * 256))[lane];
        unsigned int r7 = ((const unsigned int*)(T + (size_t)cB[3] * 256))[lane];
        float w0 = rsqrtf((float)(cnt[cA[0]] + 1));
        float w1 = rsqrtf((float)(cnt[cA[1]] + 1));
        float w2 = rsqrtf((float)(cnt[cA[2]] + 1));
        float w3 = rsqrtf((float)(cnt[cA[3]] + 1));
        float w4 = rsqrtf((float)(cnt[cB[0]] + 1));
        float w5 = rsqrtf((float)(cnt[cB[1]] + 1));
        float w6 = rsqrtf((float)(cnt[cB[2]] + 1));
        float w7 = rsqrtf((float)(cnt[cB[3]] + 1));
        a0 += w0 * fp8x4_to_f4(r0);
        a1 += w1 * fp8x4_to_f4(r1);
        a2 += w2 * fp8x4_to_f4(r2);
        a3 += w3 * fp8x4_to_f4(r3);
        a0 += w4 * fp8x4_to_f4(r4);
        a1 += w5 * fp8x4_to_f4(r5);
        a2 += w6 * fp8x4_to_f4(r6);
        a3 += w7 * fp8x4_to_f4(r7);
    }
    for (; e + 3 < deg; e += 4) {
        i32x4 c4 = *(const i32x4*)(cr + e);
        unsigned int r0 = ((const unsigned int*)(T + (size_t)c4[0] * 256))[lane];
        unsigned int r1 = ((const unsigned int*)(T + (size_t)c4[1] * 256))[lane];
        unsigned int r2 = ((const unsigned int*)(T + (size_t)c4[2] * 256))[lane];
        unsigned int r3 = ((const unsigned int*)(T + (size_t)c4[3] * 256))[lane];
        float w0 = rsqrtf((float)(cnt[c4[0]] + 1));
        float w1 = rsqrtf((float)(cnt[c4[1]] + 1));
        float w2 = rsqrtf((float)(cnt[c4[2]] + 1));
        float w3 = rsqrtf((float)(cnt[c4[3]] + 1));
        a0 += w0 * fp8x4_to_f4(r0);
        a1 += w1 * fp8x4_to_f4(r1);
        a2 += w2 * fp8x4_to_f4(r2);
        a3 += w3 * fp8x4_to_f4(r3);
    }
    for (; e < deg; e++) {
        int s0 = cr[e];
        unsigned int r0 = ((const unsigned int*)(T + (size_t)s0 * 256))[lane];
        float w0 = rsqrtf((float)(cnt[s0] + 1));
        a0 += w0 * fp8x4_to_f4(r0);
    }
    float di = rsqrtf((float)(deg + 1));
    f4 selfv = fp8x4_to_f4(((const unsigned int*)(T + (size_t)wid * 256))[lane]);
    f4 bb = ((const f4*)b)[lane];
    f4 v;
#pragma unroll
    for (int i = 0; i < 4; i++)
        v[i] = di * (a0[i] + a1[i] + a2[i] + a3[i]) + (di * di) * selfv[i] + bb[i];
    float s = wsum(v[0] + v[1] + v[2] + v[3]);
    float mean = s * (1.0f / HH);
    f4 d = v - mean;
    float ss = wsum(d[0] * d[0] + d[1] * d[1] + d[2] * d[2] + d[3] * d[3]);
    float rs = rsqrtf(ss * (1.0f / HH) + 1e-5f);
    f4 gv = ((const f4*)gam)[lane], bv = ((const f4*)bet)[lane];
    f4 o = d * rs * gv + bv;
#pragma unroll
    for (int i = 0; i < 4; i++) o[i] = fmaxf(o[i], 0.0f);
    if (resid != nullptr) {
        u16x4 rv = ((const u16x4*)(resid + (size_t)wid * HH))[lane];
#pragma unroll
        for (int i = 0; i < 4; i++) o[i] += b2f(rv[i]);
    }
    u16x4 ov;
#pragma unroll
    for (int i = 0; i < 4; i++) ov[i] = f2b(o[i]);
    ((u16x4*)(out + (size_t)wid * HH))[lane] = ov;
    if (elog != nullptr) {
        f4 wv = ((const f4*)aw)[lane];
        float dotv = wsum(b2f(ov[0]) * wv[0] + b2f(ov[1]) * wv[1] +
                          b2f(ov[2]) * wv[2] + b2f(ov[3]) * wv[3]);
        if (lane == 0) elog[wid] = expf(tanhf(dotv + ab[0]));
    }
}

// ---------------- pooling: partial weighted feature sums + partial elog sums ----------------
__device__ inline int lbound(const int* __restrict__ arr, int n, int key) {
    int lo = 0, hi = n;
    while (lo < hi) {
        int mid = (lo + hi) >> 1;
        if (arr[mid] < key) lo = mid + 1; else hi = mid;
    }
    return lo;
}

__global__ __launch_bounds__(256) void k_pool(const unsigned short* __restrict__ x3,
                                              const float* __restrict__ elog,
                                              const int* __restrict__ batch,
                                              float* __restrict__ partial,
                                              float* __restrict__ esum, int n) {
    int g = blockIdx.y, s = blockIdx.x, j = threadIdx.x;
    __shared__ int slo, shi;
    if (j == 0) { slo = lbound(batch, n, g); shi = lbound(batch, n, g + 1); }
    __syncthreads();
    int lo = slo, hi = shi;
    float a0 = 0.f, a1 = 0.f;
    int i = lo + s;
    for (; i + PSUB < hi; i += 2 * PSUB) {
        a0 += elog[i] * b2f(x3[(size_t)i * HH + j]);
        a1 += elog[i + PSUB] * b2f(x3[(size_t)(i + PSUB) * HH + j]);
    }
    if (i < hi) a0 += elog[i] * b2f(x3[(size_t)i * HH + j]);
    partial[(size_t)(g * PSUB + s) * HH + j] = a0 + a1;
    if (j < 64) {
        float es = 0.f;
        for (int t = j; (size_t)lo + s + (size_t)t * PSUB < (size_t)hi; t += 64)
            es += elog[lo + s + t * PSUB];
        es = wsum(es);
        if (j == 0) esum[g * PSUB + s] = es;
    }
}

// ---------------- tail: global elog sum + partial reduce + MLP + LN + project + L2 ----------------
__global__ __launch_bounds__(256) void k_tail(
    const float* __restrict__ partial, const float* __restrict__ esum,
    const float* __restrict__ pw1, const float* __restrict__ pb1,
    const float* __restrict__ pg, const float* __restrict__ pbe,
    const float* __restrict__ pw2, const float* __restrict__ pb2,
    float* __restrict__ out) {
    __shared__ float pl[256];
    __shared__ float ps[256];
    __shared__ float red[256];
    __shared__ float os[128];
    int g = blockIdx.x, j = threadIdx.x;
    float t = esum[j] + esum[j + 256] + esum[j + 512] + esum[j + 768];
    red[j] = t;
    __syncthreads();
    for (int s = 128; s > 0; s >>= 1) {
        if (j < s) red[j] += red[j + s];
        __syncthreads();
    }
    float inv = 1.0f / red[0];
    __syncthreads();
    float acc = 0.f;
#pragma unroll
    for (int s = 0; s < PSUB; s++) acc += partial[(size_t)(g * PSUB + s) * HH + j];
    pl[j] = acc * inv;
    __syncthreads();
    float q = pb1[j];
#pragma unroll 8
    for (int k = 0; k < 256; k++) q = fmaf(pl[k], pw1[k * 256 + j], q);
    red[j] = q;
    __syncthreads();
    for (int s = 128; s > 0; s >>= 1) {
        if (j < s) red[j] += red[j + s];
        __syncthreads();
    }
    float mean = red[0] * (1.0f / 256.0f);
    __syncthreads();
    float d = q - mean;
    red[j] = d * d;
    __syncthreads();
    for (int s = 128; s > 0; s >>= 1) {
        if (j < s) red[j] += red[j + s];
        __syncthreads();
    }
    float var = red[0] * (1.0f / 256.0f);
    __syncthreads();
    float p = fmaxf(d * rsqrtf(var + 1e-5f) * pg[j] + pbe[j], 0.0f);
    ps[j] = p;
    __syncthreads();
    if (j < 128) {
        float o = pb2[j];
#pragma unroll 8
        for (int k = 0; k < 256; k++) o = fmaf(ps[k], pw2[k * 128 + j], o);
        os[j] = o;
    }
    __syncthreads();
    float val = (j < 128) ? os[j] * os[j] : 0.f;
    red[j] = val;
    __syncthreads();
    for (int s = 128; s > 0; s >>= 1) {
        if (j < s) red[j] += red[j + s];
        __syncthreads();
    }
    float nrm = fmaxf(sqrtf(red[0]), 1e-12f);
    if (j < 128) out[g * 128 + j] = os[j] / nrm;
}

// ---------------- host ----------------
extern "C" void kernel_launch(void* const* d_in, const int* in_sizes, int n_in,
                              void* d_out, int out_size, void* d_ws, size_t ws_size,
                              hipStream_t stream) {
    const float* x      = (const float*)d_in[0];
    const int*   ei     = (const int*)d_in[1];
    const int*   batch  = (const int*)d_in[2];
    const float* enc_w  = (const float*)d_in[3];
    const float* enc_b  = (const float*)d_in[4];
    const float* enc_g  = (const float*)d_in[5];
    const float* enc_be = (const float*)d_in[6];
    const float* w1 = (const float*)d_in[7],  *b1 = (const float*)d_in[8];
    const float* g1 = (const float*)d_in[9],  *be1 = (const float*)d_in[10];
    const float* w2 = (const float*)d_in[11], *b2 = (const float*)d_in[12];
    const float* g2 = (const float*)d_in[13], *be2 = (const float*)d_in[14];
    const float* w3 = (const float*)d_in[15], *b3 = (const float*)d_in[16];
    const float* g3 = (const float*)d_in[17], *be3 = (const float*)d_in[18];
    const float* attn_w = (const float*)d_in[19], *attn_b = (const float*)d_in[20];
    const float* pw1 = (const float*)d_in[21], *pb1 = (const float*)d_in[22];
    const float* pg  = (const float*)d_in[23], *pbe = (const float*)d_in[24];
    const float* pw2 = (const float*)d_in[25], *pb2 = (const float*)d_in[26];
    float* out = (float*)d_out;

    const int* src = ei;
    const int* dst = ei + NEDGE;

    // fp8 T buffer, then bf16 region
    unsigned char* T8 = (unsigned char*)d_ws;             // [NN*256] fp8 (T1/T2/T3)
    unsigned short* Pb = (unsigned short*)(T8 + (size_t)NN * 256);  // [NN,HH] x2
    unsigned short* Qb = Pb + (size_t)NN * HH;            // [NN,HH] x1, then x3
    unsigned short* wte = Qb + (size_t)NN * HH;           // [256*128]
    unsigned short* wt1 = wte + 256 * 128;                // [256*256]
    unsigned short* wt2 = wt1 + 256 * 256;
    unsigned short* wt3 = wt2 + 256 * 256;
    // fp32/int region (16B-aligned by construction)
    float* fp = (float*)(wt3 + 256 * 256);
    float* elog    = fp;                                  // [NN]
    float* partial = elog + NN;                           // [GG*PSUB*HH]
    float* esum    = partial + (size_t)GG * PSUB * HH;    // [GG*PSUB]
    int* cnt = (int*)(esum + GG * PSUB);                  // [NN]
    int* col = cnt + NN;                                  // [NN*CSTRIDE]

    // prep: zero cnt + transpose weights (76 blocks)
    k_prep<<<76, 256, 0, stream>>>(enc_w, w1, w2, w3, wte, wt1, wt2, wt3, cnt);
    // fused encoder GEMM+LN+GEMM1 -> T1=T8 (fp8) + edge build
    k_encg1<<<313 + 1250, 256, 0, stream>>>(x, wte, wt1, enc_b, enc_g, enc_be, T8, NN,
                                            src, dst, cnt, col, NEDGE);

    dim3 gg(4, 157);   // 628 blocks, 128-row tiles (LDS W panel, XCD remap)
    // layer 1: T1=T8 -> x1=Qb
    k_aggln<<<(NN + 3) / 4, 256, 0, stream>>>(T8, cnt, col, b1, g1, be1, nullptr, Qb,
                                              nullptr, nullptr, nullptr, NN);
    // layer 2: x1=Qb -> T2=T8 (fp8) -> x2=Pb (resid Qb)
    bgemm<256><<<gg, 256, 0, stream>>>(Qb, wt2, T8, NN);
    k_aggln<<<(NN + 3) / 4, 256, 0, stream>>>(T8, cnt, col, b2, g2, be2, Qb, Pb,
                                              nullptr, nullptr, nullptr, NN);
    // layer 3: x2=Pb -> T3=T8 (fp8) -> x3=Qb (resid Pb), fused attention logits
    bgemm<256><<<gg, 256, 0, stream>>>(Pb, wt3, T8, NN);
    k_aggln<<<(NN + 3) / 4, 256, 0, stream>>>(T8, cnt, col, b3, g3, be3, Pb, Qb,
                                              attn_w, attn_b, elog, NN);
    // pooling + tail
    k_pool<<<dim3(PSUB, GG), 256, 0, stream>>>(Qb, elog, batch, partial, esum, NN);
    k_tail<<<GG, 256, 0, stream>>>(partial, esum, pw1, pb1, pg, pbe, pw2, pb2, out);
}